// Round 3
// baseline (443.762 us; speedup 1.0000x reference)
//
#include <hip/hip_runtime.h>
#include <hip/hip_bf16.h>

// ---------------------------------------------------------------------------
// Bn_bin_conv_pool: BN(batch stats) -> sign -> conv1d(K=7,pad3) -> *alpha ->
// maxpool2.  bf16 MFMA GEMM with K = Cin*KW = 448.
// v5: bconv5 = persistent blocks (256 = 1/CU) but 512 thr / 8 waves
//     (2 waves/SIMD for TLP -- v4's 1 wave/SIMD was latency-starved:
//     288k cyc observed vs ~80k modeled).  Wave tile 32o x 64l: areg
//     14x2 = 112 VGPR, acc 32, ~205 total -> fits 2/SIMD.  B dbuf LDS via
//     global_load_lds w/ source-side XOR swizzle; explicit 1-deep bfr
//     prefetch (b0/b1, static indexing).  K-loop: zero global loads.
// ---------------------------------------------------------------------------

#define N_S   64
#define C_IN  64
#define L_IN  8192
#define C_OUT 128
#define KW    7
#define L_OUT 4096
#define KDIM  448          // C_IN * KW, ordering t = k*64 + c
#define XROWS 8200         // padded rows per sample (p = l+3, valid 3..8194)

typedef float  fx4   __attribute__((ext_vector_type(4)));
typedef short  s16x8 __attribute__((ext_vector_type(8)));

// --- SFINAE dual-path MFMA wrapper: tolerates either builtin signature -----
typedef __bf16 bfx8  __attribute__((ext_vector_type(8)));
template <typename V> struct OtherFrag          { typedef bfx8  type; };
template <>           struct OtherFrag<bfx8>    { typedef s16x8 type; };

template <typename V>
static __device__ inline auto mfma_sel(V a, V b, fx4 c, int)
    -> decltype(__builtin_amdgcn_mfma_f32_16x16x32_bf16(a, b, c, 0, 0, 0)) {
  return __builtin_amdgcn_mfma_f32_16x16x32_bf16(a, b, c, 0, 0, 0);
}
template <typename V>
static __device__ inline fx4 mfma_sel(V a, V b, fx4 c, long) {
  typedef typename OtherFrag<V>::type O;
  return __builtin_amdgcn_mfma_f32_16x16x32_bf16(
      __builtin_bit_cast(O, a), __builtin_bit_cast(O, b), c, 0, 0, 0);
}
static __device__ inline fx4 mfma_bf16(s16x8 a, s16x8 b, fx4 c) {
  return mfma_sel(a, b, c, 0);
}

static __device__ inline unsigned short bin_sign(float I, float m, float s,
                                                 float g, float b) {
  // replicate reference fp32 rounding exactly: (((I-m)*s)*g)+b
  float x = __fadd_rn(__fmul_rn(__fmul_rn(__fsub_rn(I, m), s), g), b);
  return (x >= 0.0f) ? (unsigned short)0x3F80 : (unsigned short)0xBF80;
}

// --- Kernel 1: per-channel partial sums (fp64) -----------------------------
__global__ __launch_bounds__(256)
void bnstats_kernel(const float* __restrict__ x_in, double* __restrict__ partials) {
  const int c = blockIdx.x, g = blockIdx.y, tid = threadIdx.x;
  double sum = 0.0, sq = 0.0;
  for (int ns = 0; ns < 2; ++ns) {
    const float4* b4 =
        (const float4*)(x_in + ((size_t)((g * 2 + ns) * C_IN + c) << 13));
#pragma unroll
    for (int j = 0; j < 8; ++j) {
      float4 v = b4[j * 256 + tid];
      double dx = v.x, dy = v.y, dz = v.z, dw = v.w;
      sum += (dx + dy) + (dz + dw);
      sq  += (dx * dx + dy * dy) + (dz * dz + dw * dw);
    }
  }
  for (int off = 32; off > 0; off >>= 1) {
    sum += __shfl_down(sum, off);
    sq  += __shfl_down(sq,  off);
  }
  __shared__ double sd[8];
  const int wv = tid >> 6;
  if ((tid & 63) == 0) { sd[wv * 2] = sum; sd[wv * 2 + 1] = sq; }
  __syncthreads();
  if (tid == 0) {
    double S = sd[0] + sd[2] + sd[4] + sd[6];
    double Q = sd[1] + sd[3] + sd[5] + sd[7];
    partials[(c * 32 + g) * 2]     = S;
    partials[(c * 32 + g) * 2 + 1] = Q;
  }
}

// --- Kernel 2: finalize packed bn params (m, s, gamma, beta) ---------------
__global__ void bnreduce_kernel(const double* __restrict__ partials,
                                const float* __restrict__ gamma,
                                const float* __restrict__ beta,
                                float4* __restrict__ bnparams) {
  const int c = threadIdx.x;
  if (c < C_IN) {
    double S = 0.0, Q = 0.0;
    for (int g = 0; g < 32; ++g) {
      S += partials[(c * 32 + g) * 2];
      Q += partials[(c * 32 + g) * 2 + 1];
    }
    const double NL = (double)N_S * (double)L_IN;  // 524288
    double mean_d = S / NL;
    float  mean_f = (float)mean_d;
    double var_d = Q / NL - 2.0 * (double)mean_f * mean_d +
                   (double)mean_f * (double)mean_f;
    float var_f = (float)var_d;
    float vpe   = __fadd_rn(var_f, 1e-5f);
    float s_f   = (float)(1.0 / sqrt((double)vpe));
    bnparams[c] = make_float4(mean_f, s_f, gamma[c], beta[c]);
  }
}

// --- Kernel 3: repack W [o][c][k] fp32 -> Wr [o][t=k*64+c] bf16 ------------
__global__ __launch_bounds__(256)
void wrepack_kernel(const float* __restrict__ W, unsigned short* __restrict__ Wr) {
  const int f = blockIdx.x * 256 + threadIdx.x;
  if (f < C_OUT * KDIM) {
    const int o = f / KDIM, rem = f - o * KDIM;
    const int c = rem / KW, k = rem - c * KW;
    unsigned int u = __builtin_bit_cast(unsigned int, W[f]);
    u += 0x7FFFu + ((u >> 16) & 1u);  // RNE to bf16
    Wr[o * KDIM + k * C_IN + c] = (unsigned short)(u >> 16);
  }
}

// --- Kernel 3b: binarize + transpose via LDS, coalesced writes -------------
// grid (32 l-chunks, 64 samples) x 256; chunk = 256 l-positions.
// LDS tile [256 rows][128 B], row-swizzled: byte_col ^= key(row)<<4,
// key(row) = (row&7) ^ ((row>>3)&7)  (verified conflict-free both phases).
__global__ __launch_bounds__(256)
void bintrans2_kernel(const float* __restrict__ x_in,
                      const float4* __restrict__ bnparams,
                      unsigned short* __restrict__ xbt) {
  const int chunk = blockIdx.x, n = blockIdx.y, tid = threadIdx.x;
  const int lbase = chunk * 256;
  const int lane = tid & 63, w = tid >> 6;
  __shared__ __align__(16) char ldsT[256 * 128];

  // ---- phase 1: read fp32 (16B/lane coalesced), binarize, LDS-transpose ----
  const int fidx = (lbase >> 2) + lane;  // float4 index within channel row
#pragma unroll
  for (int cc = 0; cc < 4; ++cc) {
    const int c0 = w * 16 + cc * 4;
    const float4 bp0 = bnparams[c0 + 0];
    const float4 bp1 = bnparams[c0 + 1];
    const float4 bp2 = bnparams[c0 + 2];
    const float4 bp3 = bnparams[c0 + 3];
    const float4 f0 = ((const float4*)(x_in + ((size_t)(n * C_IN + c0 + 0) << 13)))[fidx];
    const float4 f1 = ((const float4*)(x_in + ((size_t)(n * C_IN + c0 + 1) << 13)))[fidx];
    const float4 f2 = ((const float4*)(x_in + ((size_t)(n * C_IN + c0 + 2) << 13)))[fidx];
    const float4 f3 = ((const float4*)(x_in + ((size_t)(n * C_IN + c0 + 3) << 13)))[fidx];
    const float e0[4] = {f0.x, f0.y, f0.z, f0.w};
    const float e1[4] = {f1.x, f1.y, f1.z, f1.w};
    const float e2[4] = {f2.x, f2.y, f2.z, f2.w};
    const float e3[4] = {f3.x, f3.y, f3.z, f3.w};
#pragma unroll
    for (int d = 0; d < 4; ++d) {
      ushort4 v;
      v.x = bin_sign(e0[d], bp0.x, bp0.y, bp0.z, bp0.w);
      v.y = bin_sign(e1[d], bp1.x, bp1.y, bp1.z, bp1.w);
      v.z = bin_sign(e2[d], bp2.x, bp2.y, bp2.z, bp2.w);
      v.w = bin_sign(e3[d], bp3.x, bp3.y, bp3.z, bp3.w);
      const int l   = 4 * lane + d;                       // local row
      const int key = ((l & 7) ^ ((l >> 3) & 7)) << 4;
      *(ushort4*)(ldsT + l * 128 + ((c0 * 2) ^ key)) = v; // 8B, 4-way max
    }
  }
  __syncthreads();

  // ---- phase 2: rows p = lbase+3 .. lbase+258, 16B/lane fully coalesced ----
  char* gout = (char*)xbt + (size_t)n * XROWS * 128 + (size_t)(lbase + 3) * 128;
#pragma unroll
  for (int i = 0; i < 8; ++i) {
    const int idx  = i * 256 + tid;
    const int row  = idx >> 3, slot = idx & 7;
    const int key  = ((row & 7) ^ ((row >> 3) & 7)) << 4;
    *(int4*)(gout + ((size_t)idx << 4)) =
        *(const int4*)(ldsT + row * 128 + ((slot << 4) ^ key));
  }
  // zero-pad rows (only edge chunks)
  int4 z4; z4.x = z4.y = z4.z = z4.w = 0;
  if (chunk == 0 && tid < 24)    // rows 0..2
    *(int4*)((char*)xbt + (size_t)n * XROWS * 128 + tid * 16) = z4;
  if (chunk == 31 && tid < 40)   // rows 8195..8199
    *(int4*)((char*)xbt + (size_t)n * XROWS * 128 + 8195ull * 128 + tid * 16) = z4;
}

// --- Kernel 4 (v5): persistent conv GEMM, 8 waves (2/SIMD), A in regs ------
// grid (4 l-quarters, 64 samples) = 256 blocks (1/CU), 512 thr (8 waves).
// Block tile 128o x 128l, T=16 tiles (2048 l).  Wave = 32o x 64l
// (og = w&3, lg = w>>2).  areg[14][2] = 112 VGPR loaded once from L2.
// B: ldsB[2][136*128], swizzle byte^=(row&7)<<4 on global src + ds_read.
// Explicit 1-deep bfr prefetch (b0/b1 named arrays, static indexing).
__global__ __launch_bounds__(512, 2)
void bconv5_kernel(const unsigned short* __restrict__ xbt,
                   const unsigned short* __restrict__ Wr,
                   const float* __restrict__ alpha,
                   float* __restrict__ out) {
  const int n  = blockIdx.y;
  const int lq = blockIdx.x;                 // 0..3 : 2048 l each
  const int tid  = threadIdx.x;
  const int lane = tid & 63, w = tid >> 6;
  const int n16 = lane & 15, quad = lane >> 4;
  const int obase = (w & 3) * 32;            // 4 o-groups
  const int lW    = (w >> 2) * 64;           // 2 l-groups

  __shared__ __align__(16) char ldsB[2][136 * 128];  // 2 x 17408 B

  // ---- A-fragments: 32o x 448k per wave, loaded once (L2-resident Wr) ----
  s16x8 areg[14][2];
  {
    const unsigned short* arow = Wr + (obase + n16) * KDIM + quad * 8;
#pragma unroll
    for (int ks = 0; ks < 14; ++ks)
#pragma unroll
      for (int ob = 0; ob < 2; ++ob)
        areg[ks][ob] = *(const s16x8*)(arow + ob * 16 * KDIM + ks * 32);
  }
  float al[8];
#pragma unroll
  for (int ob = 0; ob < 2; ++ob)
#pragma unroll
    for (int r = 0; r < 4; ++r)
      al[ob * 4 + r] = alpha[obase + ob * 16 + quad * 4 + r];

  const char* gB = (const char*)(xbt + (size_t)n * XROWS * C_IN);
  const int r_in = lane >> 3;          // 0..7 within 1KB chunk
  const int colb = (lane & 7) << 4;    // 0..112
  const int lq0  = lq * 2048;

  // stage tile t into buffer buf: rows [lq0+t*128, +136), 17 x 1KB
  auto stage = [&](int t, int buf) {
    const char* gbase = gB + (size_t)(lq0 + t * 128) * 128;
    for (int i = w; i < 17; i += 8) {
      const int row = i * 8 + r_in;
      const char* src = gbase + row * 128 + (colb ^ ((row & 7) << 4));
      __builtin_amdgcn_global_load_lds((const unsigned int*)src,
                                       (unsigned int*)(&ldsB[buf][i * 1024]),
                                       16, 0, 0);
    }
  };

  stage(0, 0);
  asm volatile("s_waitcnt vmcnt(0)");
  __syncthreads();

  const size_t outbase = (size_t)n * C_OUT * L_OUT;
  int buf = 0;
  for (int t = 0; t < 16; ++t) {
    if (t < 15) stage(t + 1, buf ^ 1);   // issue early; lands under compute

    fx4 acc[2][4];
#pragma unroll
    for (int ob = 0; ob < 2; ++ob)
#pragma unroll
      for (int lb = 0; lb < 4; ++lb)
        acc[ob][lb] = (fx4){0.f, 0.f, 0.f, 0.f};

    const char* Bb = ldsB[buf];
    // B-fragment address for (ks, lb)
    auto baddr = [&](int ks, int lb) -> const s16x8* {
      const int k   = ks >> 1;
      const int cb  = ((ks & 1) << 6) | (quad << 4);
      const int row = lW + lb * 16 + n16 + k;            // <= 133
      return (const s16x8*)(Bb + row * 128 + (cb ^ ((row & 7) << 4)));
    };

    s16x8 b0[4], b1[4];
#pragma unroll
    for (int lb = 0; lb < 4; ++lb) b0[lb] = *baddr(0, lb);

#pragma unroll
    for (int ks2 = 0; ks2 < 7; ++ks2) {
      const int ks = 2 * ks2;
      // prefetch odd step while computing even step
#pragma unroll
      for (int lb = 0; lb < 4; ++lb) b1[lb] = *baddr(ks + 1, lb);
#pragma unroll
      for (int ob = 0; ob < 2; ++ob)
#pragma unroll
        for (int lb = 0; lb < 4; ++lb)
          acc[ob][lb] = mfma_bf16(areg[ks][ob], b0[lb], acc[ob][lb]);
      if (ks2 < 6) {
#pragma unroll
        for (int lb = 0; lb < 4; ++lb) b0[lb] = *baddr(ks + 2, lb);
      }
#pragma unroll
      for (int ob = 0; ob < 2; ++ob)
#pragma unroll
        for (int lb = 0; lb < 4; ++lb)
          acc[ob][lb] = mfma_bf16(areg[ks + 1][ob], b1[lb], acc[ob][lb]);
    }

    // stage(t+1) had the whole compute phase to land: vmcnt(0) ~free here.
    asm volatile("s_waitcnt vmcnt(0)");
    __syncthreads();
    buf ^= 1;

    // epilogue AFTER the barrier: stores overlap next tile's stage+compute
    const int lstart = lq0 + t * 128;
#pragma unroll
    for (int ob = 0; ob < 2; ++ob) {
#pragma unroll
      for (int lb = 0; lb < 4; ++lb) {
        const int l_local = lW + lb * 16 + n16;
#pragma unroll
        for (int r = 0; r < 4; ++r) {
          const int o = obase + ob * 16 + quad * 4 + r;
          float v  = acc[ob][lb][r];
          float pv = __shfl_xor(v, 1);
          float mx = fmaxf(v, pv);
          if ((n16 & 1) == 0) {
            out[outbase + (size_t)o * L_OUT + ((lstart + l_local) >> 1)] =
                mx * al[ob * 4 + r];
          }
        }
      }
    }
  }
}

// --- Fallback fused kernel (round-1 path, used if ws too small) ------------
#define LT    64
#define PROWS 70
#define RS    72
__global__ __launch_bounds__(256)
void bconv_fused_kernel(const float* __restrict__ x_in,
                        const float4* __restrict__ bnparams,
                        const float* __restrict__ alpha,
                        const unsigned short* __restrict__ Wr,
                        float* __restrict__ out) {
  const int tile = blockIdx.x, n = blockIdx.y;
  const int l0 = tile * LT, tid = threadIdx.x;
  __shared__ __align__(16) unsigned short lds_xb[PROWS * RS];
  {
    const int c = tid >> 2, sub = tid & 3;
    const float4 bp = bnparams[c];
    const float* xc = x_in + ((size_t)(n * C_IN + c) << 13);
#pragma unroll
    for (int i = 0; i < 18; ++i) {
      const int p = sub * 18 + i;
      if (p < PROWS) {
        const int l = l0 + p - 3;
        unsigned short v = 0;
        if (l >= 0 && l < L_IN) v = bin_sign(xc[l], bp.x, bp.y, bp.z, bp.w);
        lds_xb[p * RS + c] = v;
      }
    }
  }
  __syncthreads();
  const int lane = tid & 63, w = tid >> 6;
  const int n16 = lane & 15, quad = lane >> 4;
  const int obase = (w & 1) * 64, lwave = (w >> 1) * 32;
  fx4 acc[4][2];
#pragma unroll
  for (int ob = 0; ob < 4; ++ob)
#pragma unroll
    for (int lb = 0; lb < 2; ++lb) acc[ob][lb] = (fx4){0.f, 0.f, 0.f, 0.f};
  const unsigned short* arow = Wr + (obase + n16) * KDIM + quad * 8;
#pragma unroll
  for (int ks = 0; ks < 14; ++ks) {
    const int k = ks >> 1, c0 = (ks & 1) * 32;
    s16x8 afr[4];
#pragma unroll
    for (int ob = 0; ob < 4; ++ob)
      afr[ob] = *(const s16x8*)(arow + ob * 16 * KDIM + ks * 32);
    s16x8 bfr[2];
#pragma unroll
    for (int lb = 0; lb < 2; ++lb) {
      const int p = lwave + lb * 16 + n16 + k;
      bfr[lb] = *(const s16x8*)(&lds_xb[p * RS + c0 + quad * 8]);
    }
#pragma unroll
    for (int ob = 0; ob < 4; ++ob)
#pragma unroll
      for (int lb = 0; lb < 2; ++lb)
        acc[ob][lb] = mfma_bf16(afr[ob], bfr[lb], acc[ob][lb]);
  }
  const size_t outbase = (size_t)n * C_OUT * L_OUT;
#pragma unroll
  for (int ob = 0; ob < 4; ++ob)
#pragma unroll
    for (int lb = 0; lb < 2; ++lb) {
      const int l_local = lwave + lb * 16 + n16;
#pragma unroll
      for (int r = 0; r < 4; ++r) {
        const int o = obase + ob * 16 + quad * 4 + r;
        float v = acc[ob][lb][r];
        float pv = __shfl_xor(v, 1);
        float mx = fmaxf(v, pv);
        if ((n16 & 1) == 0)
          out[outbase + (size_t)o * L_OUT + ((l0 + l_local) >> 1)] = mx * alpha[o];
      }
    }
}

// ---------------------------------------------------------------------------
extern "C" void kernel_launch(void* const* d_in, const int* in_sizes, int n_in,
                              void* d_out, int out_size, void* d_ws, size_t ws_size,
                              hipStream_t stream) {
  const float* x_in  = (const float*)d_in[0];
  const float* gamma = (const float*)d_in[1];
  const float* beta  = (const float*)d_in[2];
  const float* W     = (const float*)d_in[3];
  const float* alpha = (const float*)d_in[4];
  float* out = (float*)d_out;

  double*         partials = (double*)d_ws;                          // 32 KB
  float4*         bnparams = (float4*)((char*)d_ws + 32768);         // 1 KB
  unsigned short* Wr       = (unsigned short*)((char*)d_ws + 36864); // 112 KB
  unsigned short* xbt      = (unsigned short*)((char*)d_ws + 262144);
  const size_t xbt_bytes   = (size_t)N_S * XROWS * C_IN * 2;         // ~67.2 MB

  bnstats_kernel<<<dim3(64, 32), 256, 0, stream>>>(x_in, partials);
  wrepack_kernel<<<(C_OUT * KDIM + 255) / 256, 256, 0, stream>>>(W, Wr);
  bnreduce_kernel<<<1, 64, 0, stream>>>(partials, gamma, beta, bnparams);

  if (ws_size >= 262144 + xbt_bytes) {
    bintrans2_kernel<<<dim3(32, 64), 256, 0, stream>>>(x_in, bnparams, xbt);
    bconv5_kernel<<<dim3(4, 64), 512, 0, stream>>>(xbt, Wr, alpha, out);
  } else {
    bconv_fused_kernel<<<dim3(128, 64), 256, 0, stream>>>(x_in, bnparams,
                                                          alpha, Wr, out);
  }
}

// Round 4
// 362.405 us; speedup vs baseline: 1.2245x; 1.2245x over previous
//
#include <hip/hip_runtime.h>
#include <hip/hip_bf16.h>

// ---------------------------------------------------------------------------
// Bn_bin_conv_pool: BN(batch stats) -> sign -> conv1d(K=7,pad3) -> *alpha ->
// maxpool2.  bf16 MFMA GEMM with K = Cin*KW = 448.
// v6: bconv6 = persistent 256 blocks (1/CU), 512 thr / 8 waves (2/SIMD),
//     wave tile 32o x 64l.  A-fragments PINNED to AGPRs via inline-asm MFMA
//     with "a" constraint (v5's regalloc spilled at the same config:
//     VGPR_Count=128 vs ~210 demand -> scratch traffic, FETCH 2x).
//     AGPR: areg 112 + nothing else.  VGPR: acc 32 + b 16 + misc ~45.
//     B dbuf LDS via global_load_lds w/ source-side XOR swizzle (unchanged).
//     wrepack+bnreduce merged into one dispatch.
// ---------------------------------------------------------------------------

#define N_S   64
#define C_IN  64
#define L_IN  8192
#define C_OUT 128
#define KW    7
#define L_OUT 4096
#define KDIM  448          // C_IN * KW, ordering t = k*64 + c
#define XROWS 8200         // padded rows per sample (p = l+3, valid 3..8194)

typedef float  fx4   __attribute__((ext_vector_type(4)));
typedef short  s16x8 __attribute__((ext_vector_type(8)));

// MFMA with A pinned to AGPR ("a"), B in VGPR, acc in VGPR.  gfx950 allows
// A/B operands from AGPR (ISA sec.10).  Non-volatile: scheduler may hoist
// independent LDS loads across it (self-pipelining), and it cannot be DCE'd
// while acc feeds the epilogue.
static __device__ inline void mfma_a(fx4& acc, const s16x8& a, const s16x8& b) {
  asm("v_mfma_f32_16x16x32_bf16 %0, %1, %2, %0"
      : "+v"(acc)
      : "a"(a), "v"(b));
}

static __device__ inline unsigned short bin_sign(float I, float m, float s,
                                                 float g, float b) {
  // replicate reference fp32 rounding exactly: (((I-m)*s)*g)+b
  float x = __fadd_rn(__fmul_rn(__fmul_rn(__fsub_rn(I, m), s), g), b);
  return (x >= 0.0f) ? (unsigned short)0x3F80 : (unsigned short)0xBF80;
}

// --- Kernel 1: per-channel partial sums (fp64) -----------------------------
__global__ __launch_bounds__(256)
void bnstats_kernel(const float* __restrict__ x_in, double* __restrict__ partials) {
  const int c = blockIdx.x, g = blockIdx.y, tid = threadIdx.x;
  double sum = 0.0, sq = 0.0;
  for (int ns = 0; ns < 2; ++ns) {
    const float4* b4 =
        (const float4*)(x_in + ((size_t)((g * 2 + ns) * C_IN + c) << 13));
#pragma unroll
    for (int j = 0; j < 8; ++j) {
      float4 v = b4[j * 256 + tid];
      double dx = v.x, dy = v.y, dz = v.z, dw = v.w;
      sum += (dx + dy) + (dz + dw);
      sq  += (dx * dx + dy * dy) + (dz * dz + dw * dw);
    }
  }
  for (int off = 32; off > 0; off >>= 1) {
    sum += __shfl_down(sum, off);
    sq  += __shfl_down(sq,  off);
  }
  __shared__ double sd[8];
  const int wv = tid >> 6;
  if ((tid & 63) == 0) { sd[wv * 2] = sum; sd[wv * 2 + 1] = sq; }
  __syncthreads();
  if (tid == 0) {
    double S = sd[0] + sd[2] + sd[4] + sd[6];
    double Q = sd[1] + sd[3] + sd[5] + sd[7];
    partials[(c * 32 + g) * 2]     = S;
    partials[(c * 32 + g) * 2 + 1] = Q;
  }
}

// --- Kernel 2 (merged): block 0 = bn finalize; blocks 1.. = W repack -------
__global__ __launch_bounds__(256)
void bnfinish_kernel(const double* __restrict__ partials,
                     const float* __restrict__ gamma,
                     const float* __restrict__ beta,
                     float4* __restrict__ bnparams,
                     const float* __restrict__ W,
                     unsigned short* __restrict__ Wr) {
  const int b = blockIdx.x;
  if (b == 0) {
    const int c = threadIdx.x;
    if (c < C_IN) {
      double S = 0.0, Q = 0.0;
      for (int g = 0; g < 32; ++g) {
        S += partials[(c * 32 + g) * 2];
        Q += partials[(c * 32 + g) * 2 + 1];
      }
      const double NL = (double)N_S * (double)L_IN;  // 524288
      double mean_d = S / NL;
      float  mean_f = (float)mean_d;
      double var_d = Q / NL - 2.0 * (double)mean_f * mean_d +
                     (double)mean_f * (double)mean_f;
      float var_f = (float)var_d;
      float vpe   = __fadd_rn(var_f, 1e-5f);
      float s_f   = (float)(1.0 / sqrt((double)vpe));
      bnparams[c] = make_float4(mean_f, s_f, gamma[c], beta[c]);
    }
  } else {
    const int f = (b - 1) * 256 + threadIdx.x;
    if (f < C_OUT * KDIM) {
      const int o = f / KDIM, rem = f - o * KDIM;
      const int c = rem / KW, k = rem - c * KW;
      unsigned int u = __builtin_bit_cast(unsigned int, W[f]);
      u += 0x7FFFu + ((u >> 16) & 1u);  // RNE to bf16
      Wr[o * KDIM + k * C_IN + c] = (unsigned short)(u >> 16);
    }
  }
}

// --- Kernel 3b: binarize + transpose via LDS, coalesced writes -------------
// grid (32 l-chunks, 64 samples) x 256; chunk = 256 l-positions.
// LDS tile [256 rows][128 B], row-swizzled: byte_col ^= key(row)<<4,
// key(row) = (row&7) ^ ((row>>3)&7)  (conflict-free both phases; counter=0).
__global__ __launch_bounds__(256)
void bintrans2_kernel(const float* __restrict__ x_in,
                      const float4* __restrict__ bnparams,
                      unsigned short* __restrict__ xbt) {
  const int chunk = blockIdx.x, n = blockIdx.y, tid = threadIdx.x;
  const int lbase = chunk * 256;
  const int lane = tid & 63, w = tid >> 6;
  __shared__ __align__(16) char ldsT[256 * 128];

  // ---- phase 1: read fp32 (16B/lane coalesced), binarize, LDS-transpose ----
  const int fidx = (lbase >> 2) + lane;  // float4 index within channel row
#pragma unroll
  for (int cc = 0; cc < 4; ++cc) {
    const int c0 = w * 16 + cc * 4;
    const float4 bp0 = bnparams[c0 + 0];
    const float4 bp1 = bnparams[c0 + 1];
    const float4 bp2 = bnparams[c0 + 2];
    const float4 bp3 = bnparams[c0 + 3];
    const float4 f0 = ((const float4*)(x_in + ((size_t)(n * C_IN + c0 + 0) << 13)))[fidx];
    const float4 f1 = ((const float4*)(x_in + ((size_t)(n * C_IN + c0 + 1) << 13)))[fidx];
    const float4 f2 = ((const float4*)(x_in + ((size_t)(n * C_IN + c0 + 2) << 13)))[fidx];
    const float4 f3 = ((const float4*)(x_in + ((size_t)(n * C_IN + c0 + 3) << 13)))[fidx];
    const float e0[4] = {f0.x, f0.y, f0.z, f0.w};
    const float e1[4] = {f1.x, f1.y, f1.z, f1.w};
    const float e2[4] = {f2.x, f2.y, f2.z, f2.w};
    const float e3[4] = {f3.x, f3.y, f3.z, f3.w};
#pragma unroll
    for (int d = 0; d < 4; ++d) {
      ushort4 v;
      v.x = bin_sign(e0[d], bp0.x, bp0.y, bp0.z, bp0.w);
      v.y = bin_sign(e1[d], bp1.x, bp1.y, bp1.z, bp1.w);
      v.z = bin_sign(e2[d], bp2.x, bp2.y, bp2.z, bp2.w);
      v.w = bin_sign(e3[d], bp3.x, bp3.y, bp3.z, bp3.w);
      const int l   = 4 * lane + d;                       // local row
      const int key = ((l & 7) ^ ((l >> 3) & 7)) << 4;
      *(ushort4*)(ldsT + l * 128 + ((c0 * 2) ^ key)) = v; // 8B, 4-way max
    }
  }
  __syncthreads();

  // ---- phase 2: rows p = lbase+3 .. lbase+258, 16B/lane fully coalesced ----
  char* gout = (char*)xbt + (size_t)n * XROWS * 128 + (size_t)(lbase + 3) * 128;
#pragma unroll
  for (int i = 0; i < 8; ++i) {
    const int idx  = i * 256 + tid;
    const int row  = idx >> 3, slot = idx & 7;
    const int key  = ((row & 7) ^ ((row >> 3) & 7)) << 4;
    *(int4*)(gout + ((size_t)idx << 4)) =
        *(const int4*)(ldsT + row * 128 + ((slot << 4) ^ key));
  }
  // zero-pad rows (only edge chunks)
  int4 z4; z4.x = z4.y = z4.z = z4.w = 0;
  if (chunk == 0 && tid < 24)    // rows 0..2
    *(int4*)((char*)xbt + (size_t)n * XROWS * 128 + tid * 16) = z4;
  if (chunk == 31 && tid < 40)   // rows 8195..8199
    *(int4*)((char*)xbt + (size_t)n * XROWS * 128 + 8195ull * 128 + tid * 16) = z4;
}

// --- Kernel 4 (v6): persistent conv GEMM, A pinned in AGPRs ----------------
// grid (4 l-quarters, 64 samples) = 256 blocks (1/CU), 512 thr (8 waves,
// 2/SIMD).  Block tile 128o x 128l, T=16 tiles.  Wave = 32o x 64l
// (og = w&3, lg = w>>2).  areg[14][2] = 112 AGPR via "a"-constrained asm
// MFMA; acc 32 VGPR + b 16 VGPR + misc -> both halves fit, no spill.
// B: ldsB[2][136*128], swizzle byte^=(row&7)<<4 on global src + ds_read.
__global__ __launch_bounds__(512, 2)
void bconv6_kernel(const unsigned short* __restrict__ xbt,
                   const unsigned short* __restrict__ Wr,
                   const float* __restrict__ alpha,
                   float* __restrict__ out) {
  const int n  = blockIdx.y;
  const int lq = blockIdx.x;                 // 0..3 : 2048 l each
  const int tid  = threadIdx.x;
  const int lane = tid & 63, w = tid >> 6;
  const int n16 = lane & 15, quad = lane >> 4;
  const int obase = (w & 3) * 32;            // 4 o-groups
  const int lW    = (w >> 2) * 64;           // 2 l-groups

  __shared__ __align__(16) char ldsB[2][136 * 128];  // 2 x 17408 B

  // ---- A-fragments: 32o x 448k per wave, loaded once (L2-resident Wr) ----
  s16x8 areg[14][2];
  {
    const unsigned short* arow = Wr + (obase + n16) * KDIM + quad * 8;
#pragma unroll
    for (int ks = 0; ks < 14; ++ks)
#pragma unroll
      for (int ob = 0; ob < 2; ++ob)
        areg[ks][ob] = *(const s16x8*)(arow + ob * 16 * KDIM + ks * 32);
  }
  float al[8];
#pragma unroll
  for (int ob = 0; ob < 2; ++ob)
#pragma unroll
    for (int r = 0; r < 4; ++r)
      al[ob * 4 + r] = alpha[obase + ob * 16 + quad * 4 + r];

  const char* gB = (const char*)(xbt + (size_t)n * XROWS * C_IN);
  const int r_in = lane >> 3;          // 0..7 within 1KB chunk
  const int colb = (lane & 7) << 4;    // 0..112
  const int lq0  = lq * 2048;

  // stage tile t into buffer buf: rows [lq0+t*128, +136), 17 x 1KB
  auto stage = [&](int t, int buf) {
    const char* gbase = gB + (size_t)(lq0 + t * 128) * 128;
    for (int i = w; i < 17; i += 8) {
      const int row = i * 8 + r_in;
      const char* src = gbase + row * 128 + (colb ^ ((row & 7) << 4));
      __builtin_amdgcn_global_load_lds((const unsigned int*)src,
                                       (unsigned int*)(&ldsB[buf][i * 1024]),
                                       16, 0, 0);
    }
  };

  stage(0, 0);
  asm volatile("s_waitcnt vmcnt(0)");
  __syncthreads();

  const size_t outbase = (size_t)n * C_OUT * L_OUT;
  int buf = 0;
  for (int t = 0; t < 16; ++t) {
    if (t < 15) stage(t + 1, buf ^ 1);   // issue early; lands under compute

    fx4 acc[2][4];
#pragma unroll
    for (int ob = 0; ob < 2; ++ob)
#pragma unroll
      for (int lb = 0; lb < 4; ++lb)
        acc[ob][lb] = (fx4){0.f, 0.f, 0.f, 0.f};

    const char* Bb = ldsB[buf];
#pragma unroll
    for (int ks = 0; ks < 14; ++ks) {
      const int k  = ks >> 1;
      const int cb = ((ks & 1) << 6) | (quad << 4);
      s16x8 bfr[4];
#pragma unroll
      for (int lb = 0; lb < 4; ++lb) {
        const int row = lW + lb * 16 + n16 + k;          // <= 133
        bfr[lb] = *(const s16x8*)(Bb + row * 128 + (cb ^ ((row & 7) << 4)));
      }
#pragma unroll
      for (int ob = 0; ob < 2; ++ob)
#pragma unroll
        for (int lb = 0; lb < 4; ++lb)
          mfma_a(acc[ob][lb], areg[ks][ob], bfr[lb]);
    }

    // stage(t+1) had the whole compute phase to land: vmcnt(0) ~free here.
    asm volatile("s_waitcnt vmcnt(0)");
    __syncthreads();
    buf ^= 1;

    // epilogue AFTER the barrier: stores overlap next tile's stage+compute
    const int lstart = lq0 + t * 128;
#pragma unroll
    for (int ob = 0; ob < 2; ++ob) {
#pragma unroll
      for (int lb = 0; lb < 4; ++lb) {
        const int l_local = lW + lb * 16 + n16;
#pragma unroll
        for (int r = 0; r < 4; ++r) {
          const int o = obase + ob * 16 + quad * 4 + r;
          float v  = acc[ob][lb][r];
          float pv = __shfl_xor(v, 1);
          float mx = fmaxf(v, pv);
          if ((n16 & 1) == 0) {
            out[outbase + (size_t)o * L_OUT + ((lstart + l_local) >> 1)] =
                mx * al[ob * 4 + r];
          }
        }
      }
    }
  }
}

// --- Fallback fused kernel (round-1 path, used if ws too small) ------------
#define LT    64
#define PROWS 70
#define RS    72

typedef __bf16 bfx8  __attribute__((ext_vector_type(8)));
template <typename V> struct OtherFrag          { typedef bfx8  type; };
template <>           struct OtherFrag<bfx8>    { typedef s16x8 type; };

template <typename V>
static __device__ inline auto mfma_sel(V a, V b, fx4 c, int)
    -> decltype(__builtin_amdgcn_mfma_f32_16x16x32_bf16(a, b, c, 0, 0, 0)) {
  return __builtin_amdgcn_mfma_f32_16x16x32_bf16(a, b, c, 0, 0, 0);
}
template <typename V>
static __device__ inline fx4 mfma_sel(V a, V b, fx4 c, long) {
  typedef typename OtherFrag<V>::type O;
  return __builtin_amdgcn_mfma_f32_16x16x32_bf16(
      __builtin_bit_cast(O, a), __builtin_bit_cast(O, b), c, 0, 0, 0);
}
static __device__ inline fx4 mfma_bf16(s16x8 a, s16x8 b, fx4 c) {
  return mfma_sel(a, b, c, 0);
}

__global__ __launch_bounds__(256)
void bconv_fused_kernel(const float* __restrict__ x_in,
                        const float4* __restrict__ bnparams,
                        const float* __restrict__ alpha,
                        const unsigned short* __restrict__ Wr,
                        float* __restrict__ out) {
  const int tile = blockIdx.x, n = blockIdx.y;
  const int l0 = tile * LT, tid = threadIdx.x;
  __shared__ __align__(16) unsigned short lds_xb[PROWS * RS];
  {
    const int c = tid >> 2, sub = tid & 3;
    const float4 bp = bnparams[c];
    const float* xc = x_in + ((size_t)(n * C_IN + c) << 13);
#pragma unroll
    for (int i = 0; i < 18; ++i) {
      const int p = sub * 18 + i;
      if (p < PROWS) {
        const int l = l0 + p - 3;
        unsigned short v = 0;
        if (l >= 0 && l < L_IN) v = bin_sign(xc[l], bp.x, bp.y, bp.z, bp.w);
        lds_xb[p * RS + c] = v;
      }
    }
  }
  __syncthreads();
  const int lane = tid & 63, w = tid >> 6;
  const int n16 = lane & 15, quad = lane >> 4;
  const int obase = (w & 1) * 64, lwave = (w >> 1) * 32;
  fx4 acc[4][2];
#pragma unroll
  for (int ob = 0; ob < 4; ++ob)
#pragma unroll
    for (int lb = 0; lb < 2; ++lb) acc[ob][lb] = (fx4){0.f, 0.f, 0.f, 0.f};
  const unsigned short* arow = Wr + (obase + n16) * KDIM + quad * 8;
#pragma unroll
  for (int ks = 0; ks < 14; ++ks) {
    const int k = ks >> 1, c0 = (ks & 1) * 32;
    s16x8 afr[4];
#pragma unroll
    for (int ob = 0; ob < 4; ++ob)
      afr[ob] = *(const s16x8*)(arow + ob * 16 * KDIM + ks * 32);
    s16x8 bfr[2];
#pragma unroll
    for (int lb = 0; lb < 2; ++lb) {
      const int p = lwave + lb * 16 + n16 + k;
      bfr[lb] = *(const s16x8*)(&lds_xb[p * RS + c0 + quad * 8]);
    }
#pragma unroll
    for (int ob = 0; ob < 4; ++ob)
#pragma unroll
      for (int lb = 0; lb < 2; ++lb)
        acc[ob][lb] = mfma_bf16(afr[ob], bfr[lb], acc[ob][lb]);
  }
  const size_t outbase = (size_t)n * C_OUT * L_OUT;
#pragma unroll
  for (int ob = 0; ob < 4; ++ob)
#pragma unroll
    for (int lb = 0; lb < 2; ++lb) {
      const int l_local = lwave + lb * 16 + n16;
#pragma unroll
      for (int r = 0; r < 4; ++r) {
        const int o = obase + ob * 16 + quad * 4 + r;
        float v = acc[ob][lb][r];
        float pv = __shfl_xor(v, 1);
        float mx = fmaxf(v, pv);
        if ((n16 & 1) == 0)
          out[outbase + (size_t)o * L_OUT + ((l0 + l_local) >> 1)] = mx * alpha[o];
      }
    }
}

// ---------------------------------------------------------------------------
extern "C" void kernel_launch(void* const* d_in, const int* in_sizes, int n_in,
                              void* d_out, int out_size, void* d_ws, size_t ws_size,
                              hipStream_t stream) {
  const float* x_in  = (const float*)d_in[0];
  const float* gamma = (const float*)d_in[1];
  const float* beta  = (const float*)d_in[2];
  const float* W     = (const float*)d_in[3];
  const float* alpha = (const float*)d_in[4];
  float* out = (float*)d_out;

  double*         partials = (double*)d_ws;                          // 32 KB
  float4*         bnparams = (float4*)((char*)d_ws + 32768);         // 1 KB
  unsigned short* Wr       = (unsigned short*)((char*)d_ws + 36864); // 112 KB
  unsigned short* xbt      = (unsigned short*)((char*)d_ws + 262144);
  const size_t xbt_bytes   = (size_t)N_S * XROWS * C_IN * 2;         // ~67.2 MB

  bnstats_kernel<<<dim3(64, 32), 256, 0, stream>>>(x_in, partials);
  bnfinish_kernel<<<1 + (C_OUT * KDIM + 255) / 256, 256, 0, stream>>>(
      partials, gamma, beta, bnparams, W, Wr);

  if (ws_size >= 262144 + xbt_bytes) {
    bintrans2_kernel<<<dim3(32, 64), 256, 0, stream>>>(x_in, bnparams, xbt);
    bconv6_kernel<<<dim3(4, 64), 512, 0, stream>>>(xbt, Wr, alpha, out);
  } else {
    bconv_fused_kernel<<<dim3(128, 64), 256, 0, stream>>>(x_in, bnparams,
                                                          alpha, Wr, out);
  }
}